// Round 4
// baseline (176.363 us; speedup 1.0000x reference)
//
#include <hip/hip_runtime.h>
#include <math.h>

#define N_SRC 16384
#define M_REF 16384
#define DEMB  256
#define KNN_K 16
#define CAP   128   // candidate buffer per src point (expected ~55 total, validated)

// ---------------- Kernel A: W_sym = triu(W) + triu(W)^T ----------------
__global__ void wsym_kernel(const float* __restrict__ W, float* __restrict__ wsym) {
    int i = blockIdx.x;
    int j = threadIdx.x;
    float a = (j >= i) ? W[i * DEMB + j] : 0.f;
    float b = (i >= j) ? W[j * DEMB + i] : 0.f;
    wsym[i * DEMB + j] = a + b;
}

// ---------------- Kernel A2: pack ref_points -> (x,y,z,|r|^2) ----------------
__global__ void pack_kernel(const float* __restrict__ rp, float4* __restrict__ out) {
    int i = blockIdx.x * 256 + threadIdx.x;
    float x = rp[i * 3 + 0], y = rp[i * 3 + 1], z = rp[i * 3 + 2];
    out[i] = make_float4(x, y, z, fmaf(x, x, fmaf(y, y, z * z)));
}

// ---------------- Kernel B: q = src_feats @ W_sym ----------------
// 32 rows/block, 256 threads. Thread (c0=t&63, rg=t>>6): rows rg*8..+7,
// cols c0+cc*64. W_sym symmetry -> weight loads are lane-consecutive
// (coalesced). 128 fma per 16 global + 8 (broadcast) LDS loads.
__global__ void __launch_bounds__(256) q_kernel(const float* __restrict__ src_feats,
                                                const float* __restrict__ wsym,
                                                float* __restrict__ q) {
    __shared__ __align__(16) float sf[32][DEMB];
    int n0 = blockIdx.x * 32;
    int tid = threadIdx.x;
    int c0 = tid & 63;
    int rg = tid >> 6;
    {
        int c = c0 * 4;
        #pragma unroll
        for (int rr = 0; rr < 8; ++rr) {
            int r = rr * 4 + rg;
            *(float4*)&sf[r][c] = *(const float4*)&src_feats[(size_t)(n0 + r) * DEMB + c];
        }
    }
    __syncthreads();

    float acc[8][4];
    #pragma unroll
    for (int rr = 0; rr < 8; ++rr)
        #pragma unroll
        for (int cc = 0; cc < 4; ++cc) acc[rr][cc] = 0.f;

    for (int c4 = 0; c4 < 64; ++c4) {
        float wv[4][4];   // [j][cc] = W_sym[c4*4+j][c0+cc*64] (== transposed slice)
        #pragma unroll
        for (int j = 0; j < 4; ++j)
            #pragma unroll
            for (int cc = 0; cc < 4; ++cc)
                wv[j][cc] = wsym[(size_t)(c4 * 4 + j) * DEMB + c0 + cc * 64];
        #pragma unroll
        for (int rr = 0; rr < 8; ++rr) {
            float4 s = *(const float4*)&sf[rg * 8 + rr][c4 * 4];
            #pragma unroll
            for (int cc = 0; cc < 4; ++cc) {
                float a = acc[rr][cc];
                a = fmaf(s.x, wv[0][cc], a);
                a = fmaf(s.y, wv[1][cc], a);
                a = fmaf(s.z, wv[2][cc], a);
                a = fmaf(s.w, wv[3][cc], a);
                acc[rr][cc] = a;
            }
        }
    }
    #pragma unroll
    for (int rr = 0; rr < 8; ++rr)
        #pragma unroll
        for (int cc = 0; cc < 4; ++cc)
            q[(size_t)(n0 + rg * 8 + rr) * DEMB + (c0 + cc * 64)] = acc[rr][cc];
}

// ---------------- bitonic sort of (d2, idx) pairs across 64 lanes ----------------
__device__ __forceinline__ void sort64_kv(float& vd, int& vi, int lane) {
    #pragma unroll
    for (int k = 2; k <= 64; k <<= 1) {
        #pragma unroll
        for (int j = k >> 1; j > 0; j >>= 1) {
            float od = __shfl_xor(vd, j, 64);
            int   oi = __shfl_xor(vi, j, 64);
            bool keep_min = (((lane & j) == 0) == ((lane & k) == 0));
            bool oless = (od < vd) || (od == vd && oi < vi);
            bool take = (keep_min == oless);
            vd = take ? od : vd;
            vi = take ? oi : vi;
        }
    }
}

// ---------------- Kernel C: exact KNN ----------------
// Block = 128 threads = 2 waves = 2 ref-halves, one group of 8 src points.
// Grid 2048 -> 16 blocks/CU -> 32 waves/CU (100% occupancy cap).
// Per wave: tau = 16th-smallest lane-min of its half (provable bound),
// then gated LDS append; exact bitonic top-16, (d2,idx) lexicographic.
__global__ void __launch_bounds__(128) knn_kernel(const float* __restrict__ src_points,
                                                  const float4* __restrict__ refp4,
                                                  float* __restrict__ kd2,
                                                  int* __restrict__ kidx) {
    const float INF = 3.0e38f;
    int tid = threadIdx.x;
    int h = tid >> 6, lane = tid & 63;
    int n0 = blockIdx.x * 8;

    __shared__ float cd[8][CAP];
    __shared__ int   ci[8][CAP];
    __shared__ int   cnt[8];
    if (tid < 8) cnt[tid] = 0;

    float m2x[8], m2y[8], m2z[8], sn2[8];
    #pragma unroll
    for (int b = 0; b < 8; ++b) {
        float sx = src_points[(n0 + b) * 3 + 0];
        float sy = src_points[(n0 + b) * 3 + 1];
        float sz = src_points[(n0 + b) * 3 + 2];
        m2x[b] = -2.f * sx; m2y[b] = -2.f * sy; m2z[b] = -2.f * sz;
        sn2[b] = fmaf(sx, sx, fmaf(sy, sy, sz * sz));
    }
    __syncthreads();

    const int base = h * (M_REF / 2);

    // ---- pass 1: per-lane min of d2' = |r|^2 - 2 r.s, 2x unrolled ----
    float mind[8];
    #pragma unroll
    for (int b = 0; b < 8; ++b) mind[b] = INF;
    for (int it = 0; it < 128; it += 2) {
        float4 r0 = refp4[base + it * 64 + lane];
        float4 r1 = refp4[base + (it + 1) * 64 + lane];
        #pragma unroll
        for (int b = 0; b < 8; ++b) {
            float d0 = fmaf(r0.x, m2x[b], r0.w);
            d0 = fmaf(r0.y, m2y[b], d0);
            d0 = fmaf(r0.z, m2z[b], d0);
            float d1 = fmaf(r1.x, m2x[b], r1.w);
            d1 = fmaf(r1.y, m2y[b], d1);
            d1 = fmaf(r1.z, m2z[b], d1);
            mind[b] = fminf(mind[b], fminf(d0, d1));
        }
    }

    float tau[8];
    #pragma unroll
    for (int b = 0; b < 8; ++b) {
        float v = mind[b];
        #pragma unroll
        for (int k = 2; k <= 64; k <<= 1) {
            #pragma unroll
            for (int j = k >> 1; j > 0; j >>= 1) {
                float o = __shfl_xor(v, j, 64);
                bool lower = (lane & j) == 0;
                bool up = (lane & k) == 0;
                float mn = fminf(v, o), mx = fmaxf(v, o);
                v = (lower == up) ? mn : mx;
            }
        }
        tau[b] = __shfl(v, 15, 64);
    }

    // ---- pass 2: gated append ----
    for (int it = 0; it < 128; it += 2) {
        int i0 = base + it * 64 + lane;
        float4 r0 = refp4[i0];
        float4 r1 = refp4[i0 + 64];
        #pragma unroll
        for (int b = 0; b < 8; ++b) {
            float d0 = fmaf(r0.x, m2x[b], r0.w);
            d0 = fmaf(r0.y, m2y[b], d0);
            d0 = fmaf(r0.z, m2z[b], d0);
            float d1 = fmaf(r1.x, m2x[b], r1.w);
            d1 = fmaf(r1.y, m2y[b], d1);
            d1 = fmaf(r1.z, m2z[b], d1);
            if (d0 <= tau[b]) {
                int p = atomicAdd(&cnt[b], 1);
                if (p < CAP) { cd[b][p] = d0; ci[b][p] = i0; }
            }
            if (d1 <= tau[b]) {
                int p = atomicAdd(&cnt[b], 1);
                if (p < CAP) { cd[b][p] = d1; ci[b][p] = i0 + 64; }
            }
        }
    }
    __syncthreads();

    // ---- selection: wave h does src h*4..h*4+3 ----
    #pragma unroll
    for (int bb = 0; bb < 4; ++bb) {
        int b = h * 4 + bb;
        int count = cnt[b];
        if (count > CAP) count = CAP;
        float vd = (lane < count) ? cd[b][lane] : INF;
        int   vi = (lane < count) ? ci[b][lane] : 0x7fffffff;
        sort64_kv(vd, vi, lane);
        int done = 64;
        while (done < count) {
            if (lane >= 16) {
                int p = done + (lane - 16);
                vd = (p < count) ? cd[b][p] : INF;
                vi = (p < count) ? ci[b][p] : 0x7fffffff;
            }
            sort64_kv(vd, vi, lane);
            done += 48;
        }
        if (lane < KNN_K) {
            kd2[(size_t)(n0 + b) * KNN_K + lane] = vd + sn2[b];
            kidx[(size_t)(n0 + b) * KNN_K + lane] = vi;
        }
    }
}

// ---------------- Kernel D: scores, softmax, corres, w ----------------
// One wave per src point; lane owns 4 channels (float4 at c = lane*4).
// n forced wave-uniform via readfirstlane -> scalar loads for idx/d2/xyz.
__global__ void __launch_bounds__(256) score_kernel(const float* __restrict__ q,
                                                    const float* __restrict__ ref_feats,
                                                    const float* __restrict__ ref_points,
                                                    const float* __restrict__ src_points,
                                                    const float* __restrict__ kd2,
                                                    const int* __restrict__ kidx,
                                                    float* __restrict__ out) {
    int wave = threadIdx.x >> 6;
    int lane = threadIdx.x & 63;
    int n = __builtin_amdgcn_readfirstlane(blockIdx.x * 4 + wave);

    float4 qv = *(const float4*)&q[(size_t)n * DEMB + lane * 4];

    int idx[KNN_K]; float d2[KNN_K];
    #pragma unroll
    for (int k = 0; k < KNN_K; ++k) {
        idx[k] = __builtin_amdgcn_readfirstlane(kidx[(size_t)n * KNN_K + k]);
        d2[k]  = kd2[(size_t)n * KNN_K + k];
    }

    float sc[KNN_K];
    #pragma unroll
    for (int k = 0; k < KNN_K; ++k) {
        float4 r = *(const float4*)&ref_feats[(size_t)idx[k] * DEMB + lane * 4];
        float p = fmaf(r.x, qv.x, fmaf(r.y, qv.y, fmaf(r.z, qv.z, r.w * qv.w)));
        #pragma unroll
        for (int off = 1; off < 64; off <<= 1) p += __shfl_xor(p, off, 64);
        sc[k] = p;
    }

    float tv[KNN_K];
    #pragma unroll
    for (int k = 0; k < KNN_K; ++k) {
        float wt = fmaxf(0.f, fmaf(-2.f, d2[k], 1.f));
        tv[k] = sc[k] * wt;
    }
    float m = tv[0];
    #pragma unroll
    for (int k = 1; k < KNN_K; ++k) m = fmaxf(m, tv[k]);
    float e[KNN_K], s = 0.f;
    #pragma unroll
    for (int k = 0; k < KNN_K; ++k) { e[k] = expf(tv[k] - m); s += e[k]; }

    float cx = 0.f, cy = 0.f, cz = 0.f;
    #pragma unroll
    for (int k = 0; k < KNN_K; ++k) {
        float rx = ref_points[idx[k] * 3 + 0];
        float ry = ref_points[idx[k] * 3 + 1];
        float rz = ref_points[idx[k] * 3 + 2];
        cx = fmaf(e[k], rx, cx);
        cy = fmaf(e[k], ry, cy);
        cz = fmaf(e[k], rz, cz);
    }
    float inv = 1.f / s;
    cx *= inv; cy *= inv; cz *= inv;

    if (lane == 0) {
        float ssx = src_points[n * 3 + 0];
        float ssy = src_points[n * 3 + 1];
        float ssz = src_points[n * 3 + 2];
        float dx = ssx - cx, dy = ssy - cy, dz = ssz - cz;
        float dist = sqrtf(fmaf(dx, dx, fmaf(dy, dy, dz * dz)));
        float w = fmaxf(0.f, fmaf(-2.f, dist, 1.f));
        out[(size_t)n * 3 + 0] = cx;
        out[(size_t)n * 3 + 1] = cy;
        out[(size_t)n * 3 + 2] = cz;
        out[(size_t)N_SRC * 3 + n] = w;
    }
}

extern "C" void kernel_launch(void* const* d_in, const int* in_sizes, int n_in,
                              void* d_out, int out_size, void* d_ws, size_t ws_size,
                              hipStream_t stream) {
    const float* ref_points = (const float*)d_in[0];
    const float* src_points = (const float*)d_in[1];
    const float* ref_feats  = (const float*)d_in[2];
    const float* src_feats  = (const float*)d_in[3];
    const float* W          = (const float*)d_in[4];
    float* out = (float*)d_out;

    float*  wsym  = (float*)d_ws;
    float4* refp4 = (float4*)(wsym + DEMB * DEMB);
    float*  q     = (float*)(refp4 + M_REF);
    float*  kd2   = q + (size_t)N_SRC * DEMB;
    int*    kidx  = (int*)(kd2 + (size_t)N_SRC * KNN_K);

    wsym_kernel<<<DEMB, DEMB, 0, stream>>>(W, wsym);
    pack_kernel<<<M_REF / 256, 256, 0, stream>>>(ref_points, refp4);
    q_kernel<<<N_SRC / 32, 256, 0, stream>>>(src_feats, wsym, q);
    knn_kernel<<<N_SRC / 8, 128, 0, stream>>>(src_points, refp4, kd2, kidx);
    score_kernel<<<N_SRC / 4, 256, 0, stream>>>(q, ref_feats, ref_points, src_points, kd2, kidx, out);
}

// Round 5
// 167.758 us; speedup vs baseline: 1.0513x; 1.0513x over previous
//
#include <hip/hip_runtime.h>
#include <math.h>

#define N_SRC 16384
#define M_REF 16384
#define DEMB  256
#define KNN_K 16
#define CAP   288    // candidates/src; expected ~120, 2.4x margin (ratio validated R2-R4)

#define KNN_BLOCKS (N_SRC / 8)    // 2048
#define Q_BLOCKS   (N_SRC / 16)   // 1024

// LDS union: knn part = cd(8*CAP*4) + ci(8*CAP*4) + cnt(32) + stau(128) = 18592
//            q part   = 16*256*4 = 16384
#define SMEM_BYTES (8 * CAP * 8 + 32 + 128)

// ---------------- Kernel A: W_sym = triu(W) + triu(W)^T ----------------
__global__ void wsym_kernel(const float* __restrict__ W, float* __restrict__ wsym) {
    int i = blockIdx.x;
    int j = threadIdx.x;
    float a = (j >= i) ? W[i * DEMB + j] : 0.f;
    float b = (i >= j) ? W[j * DEMB + i] : 0.f;
    wsym[i * DEMB + j] = a + b;
}

// ---------------- Kernel A2: pack ref_points -> (x,y,z,|r|^2) ----------------
__global__ void pack_kernel(const float* __restrict__ rp, float4* __restrict__ out) {
    int i = blockIdx.x * 256 + threadIdx.x;
    float x = rp[i * 3 + 0], y = rp[i * 3 + 1], z = rp[i * 3 + 2];
    out[i] = make_float4(x, y, z, fmaf(x, x, fmaf(y, y, z * z)));
}

// ---------------- bitonic sort of (d2, idx) pairs across 64 lanes ----------------
__device__ __forceinline__ void sort64_kv(float& vd, int& vi, int lane) {
    #pragma unroll
    for (int k = 2; k <= 64; k <<= 1) {
        #pragma unroll
        for (int j = k >> 1; j > 0; j >>= 1) {
            float od = __shfl_xor(vd, j, 64);
            int   oi = __shfl_xor(vi, j, 64);
            bool keep_min = (((lane & j) == 0) == ((lane & k) == 0));
            bool oless = (od < vd) || (od == vd && oi < vi);
            bool take = (keep_min == oless);
            vd = take ? od : vd;
            vi = take ? oi : vi;
        }
    }
}

// ---------------- Fused kernel: KNN (blocks [0,2048)) + q-GEMM (blocks [2048,3072)) ----
// KNN: 256 thr = 4 waves = 4 ref-quarters, 8 src/block. Grid-> 8 blk/CU x 4 waves = 100% occ.
//   pass 1: each wave scans first 2048 refs of its quarter; tau_h = 16th-smallest
//   lane-min (16 real distances of distinct refs => sound global bound).
//   tau* = min_h tau_h (min of sound bounds is sound). pass 2: full quarter scan
//   gated at tau*; LDS append; exact bitonic top-16 with (d2,idx) tie-break.
// Q: q = src_feats @ W_sym, 16 rows/block, symmetry-coalesced weight loads.
__global__ void __launch_bounds__(256, 8) fused_kernel(
        const float* __restrict__ src_points, const float4* __restrict__ refp4,
        const float* __restrict__ src_feats,  const float* __restrict__ wsym,
        float* __restrict__ kd2, int* __restrict__ kidx, float* __restrict__ q) {
    __shared__ __align__(16) char smem[SMEM_BYTES];
    int tid = threadIdx.x;

    if (blockIdx.x < KNN_BLOCKS) {
        // ================= KNN part =================
        const float INF = 3.0e38f;
        float (*cd)[CAP] = (float(*)[CAP])smem;
        int   (*ci)[CAP] = (int(*)[CAP])(smem + 8 * CAP * 4);
        int*   cnt       = (int*)(smem + 8 * CAP * 8);
        float (*stau)[8] = (float(*)[8])(smem + 8 * CAP * 8 + 32);

        int h = tid >> 6, lane = tid & 63;
        int n0 = blockIdx.x * 8;
        if (tid < 8) cnt[tid] = 0;

        float m2x[8], m2y[8], m2z[8], sn2[8];   // wave-uniform -> SGPRs
        #pragma unroll
        for (int b = 0; b < 8; ++b) {
            float sx = src_points[(n0 + b) * 3 + 0];
            float sy = src_points[(n0 + b) * 3 + 1];
            float sz = src_points[(n0 + b) * 3 + 2];
            m2x[b] = -2.f * sx; m2y[b] = -2.f * sy; m2z[b] = -2.f * sz;
            sn2[b] = fmaf(sx, sx, fmaf(sy, sy, sz * sz));
        }

        const int qbase = h * (M_REF / 4);

        // ---- pass 1: subsample (first 2048 refs of quarter), per-lane min ----
        float mind[8];
        #pragma unroll
        for (int b = 0; b < 8; ++b) mind[b] = INF;
        for (int it = 0; it < 32; it += 2) {
            float4 r0 = refp4[qbase + it * 64 + lane];
            float4 r1 = refp4[qbase + (it + 1) * 64 + lane];
            #pragma unroll
            for (int b = 0; b < 8; ++b) {
                float d0 = fmaf(r0.x, m2x[b], r0.w);
                d0 = fmaf(r0.y, m2y[b], d0);
                d0 = fmaf(r0.z, m2z[b], d0);
                float d1 = fmaf(r1.x, m2x[b], r1.w);
                d1 = fmaf(r1.y, m2y[b], d1);
                d1 = fmaf(r1.z, m2z[b], d1);
                mind[b] = fminf(mind[b], fminf(d0, d1));
            }
        }

        // tau_h per src: bitonic sort lane-mins, take 16th smallest
        float tauh[8];
        #pragma unroll
        for (int b = 0; b < 8; ++b) {
            float v = mind[b];
            #pragma unroll
            for (int k = 2; k <= 64; k <<= 1) {
                #pragma unroll
                for (int j = k >> 1; j > 0; j >>= 1) {
                    float o = __shfl_xor(v, j, 64);
                    bool lower = (lane & j) == 0;
                    bool up = (lane & k) == 0;
                    float mn = fminf(v, o), mx = fmaxf(v, o);
                    v = (lower == up) ? mn : mx;
                }
            }
            tauh[b] = __shfl(v, 15, 64);
        }
        if (lane == 0) {
            #pragma unroll
            for (int b = 0; b < 8; ++b) stau[h][b] = tauh[b];
        }
        __syncthreads();
        float taul[8];
        #pragma unroll
        for (int b = 0; b < 8; ++b)
            taul[b] = fminf(fminf(stau[0][b], stau[1][b]),
                            fminf(stau[2][b], stau[3][b]));

        // ---- pass 2: full quarter scan, gated append ----
        for (int it = 0; it < 64; it += 2) {
            int i0 = qbase + it * 64 + lane;
            float4 r0 = refp4[i0];
            float4 r1 = refp4[i0 + 64];
            #pragma unroll
            for (int b = 0; b < 8; ++b) {
                float d0 = fmaf(r0.x, m2x[b], r0.w);
                d0 = fmaf(r0.y, m2y[b], d0);
                d0 = fmaf(r0.z, m2z[b], d0);
                float d1 = fmaf(r1.x, m2x[b], r1.w);
                d1 = fmaf(r1.y, m2y[b], d1);
                d1 = fmaf(r1.z, m2z[b], d1);
                if (d0 <= taul[b]) {
                    int p = atomicAdd(&cnt[b], 1);
                    if (p < CAP) { cd[b][p] = d0; ci[b][p] = i0; }
                }
                if (d1 <= taul[b]) {
                    int p = atomicAdd(&cnt[b], 1);
                    if (p < CAP) { cd[b][p] = d1; ci[b][p] = i0 + 64; }
                }
            }
        }
        __syncthreads();

        // ---- selection: wave h does srcs 2h, 2h+1 ----
        #pragma unroll
        for (int bb = 0; bb < 2; ++bb) {
            int b = h * 2 + bb;
            int count = cnt[b];
            if (count > CAP) count = CAP;
            float vd = (lane < count) ? cd[b][lane] : INF;
            int   vi = (lane < count) ? ci[b][lane] : 0x7fffffff;
            sort64_kv(vd, vi, lane);
            int done = 64;
            while (done < count) {
                if (lane >= 16) {
                    int p = done + (lane - 16);
                    vd = (p < count) ? cd[b][p] : INF;
                    vi = (p < count) ? ci[b][p] : 0x7fffffff;
                }
                sort64_kv(vd, vi, lane);
                done += 48;
            }
            if (lane < KNN_K) {
                kd2[(size_t)(n0 + b) * KNN_K + lane] = vd + sn2[b];
                kidx[(size_t)(n0 + b) * KNN_K + lane] = vi;
            }
        }
    } else {
        // ================= q-GEMM part =================
        float (*sf)[DEMB] = (float(*)[DEMB])smem;
        int n0 = (blockIdx.x - KNN_BLOCKS) * 16;
        int c0 = tid & 63;
        int rg = tid >> 6;
        {
            int c = c0 * 4;
            #pragma unroll
            for (int rr = 0; rr < 4; ++rr) {
                int r = rr * 4 + rg;
                *(float4*)&sf[r][c] = *(const float4*)&src_feats[(size_t)(n0 + r) * DEMB + c];
            }
        }
        __syncthreads();

        float acc[4][4];
        #pragma unroll
        for (int rr = 0; rr < 4; ++rr)
            #pragma unroll
            for (int cc = 0; cc < 4; ++cc) acc[rr][cc] = 0.f;

        for (int c4 = 0; c4 < 64; ++c4) {
            float wv[4][4];   // [j][cc] = W_sym[c4*4+j][c0+cc*64] (symmetric slice, coalesced)
            #pragma unroll
            for (int j = 0; j < 4; ++j)
                #pragma unroll
                for (int cc = 0; cc < 4; ++cc)
                    wv[j][cc] = wsym[(size_t)(c4 * 4 + j) * DEMB + c0 + cc * 64];
            #pragma unroll
            for (int rr = 0; rr < 4; ++rr) {
                float4 s = *(const float4*)&sf[rg * 4 + rr][c4 * 4];
                #pragma unroll
                for (int cc = 0; cc < 4; ++cc) {
                    float a = acc[rr][cc];
                    a = fmaf(s.x, wv[0][cc], a);
                    a = fmaf(s.y, wv[1][cc], a);
                    a = fmaf(s.z, wv[2][cc], a);
                    a = fmaf(s.w, wv[3][cc], a);
                    acc[rr][cc] = a;
                }
            }
        }
        #pragma unroll
        for (int rr = 0; rr < 4; ++rr)
            #pragma unroll
            for (int cc = 0; cc < 4; ++cc)
                q[(size_t)(n0 + rg * 4 + rr) * DEMB + (c0 + cc * 64)] = acc[rr][cc];
    }
}

// ---------------- Kernel D: scores, softmax, corres, w ----------------
__global__ void __launch_bounds__(256) score_kernel(const float* __restrict__ q,
                                                    const float* __restrict__ ref_feats,
                                                    const float* __restrict__ ref_points,
                                                    const float* __restrict__ src_points,
                                                    const float* __restrict__ kd2,
                                                    const int* __restrict__ kidx,
                                                    float* __restrict__ out) {
    int wave = threadIdx.x >> 6;
    int lane = threadIdx.x & 63;
    int n = __builtin_amdgcn_readfirstlane(blockIdx.x * 4 + wave);

    float4 qv = *(const float4*)&q[(size_t)n * DEMB + lane * 4];

    int idx[KNN_K]; float d2[KNN_K];
    #pragma unroll
    for (int k = 0; k < KNN_K; ++k) {
        idx[k] = __builtin_amdgcn_readfirstlane(kidx[(size_t)n * KNN_K + k]);
        d2[k]  = kd2[(size_t)n * KNN_K + k];
    }

    float sc[KNN_K];
    #pragma unroll
    for (int k = 0; k < KNN_K; ++k) {
        float4 r = *(const float4*)&ref_feats[(size_t)idx[k] * DEMB + lane * 4];
        float p = fmaf(r.x, qv.x, fmaf(r.y, qv.y, fmaf(r.z, qv.z, r.w * qv.w)));
        #pragma unroll
        for (int off = 1; off < 64; off <<= 1) p += __shfl_xor(p, off, 64);
        sc[k] = p;
    }

    float tv[KNN_K];
    #pragma unroll
    for (int k = 0; k < KNN_K; ++k) {
        float wt = fmaxf(0.f, fmaf(-2.f, d2[k], 1.f));
        tv[k] = sc[k] * wt;
    }
    float m = tv[0];
    #pragma unroll
    for (int k = 1; k < KNN_K; ++k) m = fmaxf(m, tv[k]);
    float e[KNN_K], s = 0.f;
    #pragma unroll
    for (int k = 0; k < KNN_K; ++k) { e[k] = expf(tv[k] - m); s += e[k]; }

    float cx = 0.f, cy = 0.f, cz = 0.f;
    #pragma unroll
    for (int k = 0; k < KNN_K; ++k) {
        float rx = ref_points[idx[k] * 3 + 0];
        float ry = ref_points[idx[k] * 3 + 1];
        float rz = ref_points[idx[k] * 3 + 2];
        cx = fmaf(e[k], rx, cx);
        cy = fmaf(e[k], ry, cy);
        cz = fmaf(e[k], rz, cz);
    }
    float inv = 1.f / s;
    cx *= inv; cy *= inv; cz *= inv;

    if (lane == 0) {
        float ssx = src_points[n * 3 + 0];
        float ssy = src_points[n * 3 + 1];
        float ssz = src_points[n * 3 + 2];
        float dx = ssx - cx, dy = ssy - cy, dz = ssz - cz;
        float dist = sqrtf(fmaf(dx, dx, fmaf(dy, dy, dz * dz)));
        float w = fmaxf(0.f, fmaf(-2.f, dist, 1.f));
        out[(size_t)n * 3 + 0] = cx;
        out[(size_t)n * 3 + 1] = cy;
        out[(size_t)n * 3 + 2] = cz;
        out[(size_t)N_SRC * 3 + n] = w;
    }
}

extern "C" void kernel_launch(void* const* d_in, const int* in_sizes, int n_in,
                              void* d_out, int out_size, void* d_ws, size_t ws_size,
                              hipStream_t stream) {
    const float* ref_points = (const float*)d_in[0];
    const float* src_points = (const float*)d_in[1];
    const float* ref_feats  = (const float*)d_in[2];
    const float* src_feats  = (const float*)d_in[3];
    const float* W          = (const float*)d_in[4];
    float* out = (float*)d_out;

    float*  wsym  = (float*)d_ws;
    float4* refp4 = (float4*)(wsym + DEMB * DEMB);
    float*  q     = (float*)(refp4 + M_REF);
    float*  kd2   = q + (size_t)N_SRC * DEMB;
    int*    kidx  = (int*)(kd2 + (size_t)N_SRC * KNN_K);

    wsym_kernel<<<DEMB, DEMB, 0, stream>>>(W, wsym);
    pack_kernel<<<M_REF / 256, 256, 0, stream>>>(ref_points, refp4);
    fused_kernel<<<KNN_BLOCKS + Q_BLOCKS, 256, 0, stream>>>(
        src_points, refp4, src_feats, wsym, kd2, kidx, q);
    score_kernel<<<N_SRC / 4, 256, 0, stream>>>(q, ref_feats, ref_points, src_points, kd2, kidx, out);
}